// Round 1
// baseline (7153.365 us; speedup 1.0000x reference)
//
#include <hip/hip_runtime.h>
#include <math.h>

#define BB 64
#define NN 256
#define MM 256
#define EPSF 1e-7f

// ---------- helpers ----------

__device__ __forceinline__ void iou_diou(const float4 pb, const float4 tb,
                                         float& iou, float& diou) {
    // cxcywh -> xyxy
    float x1 = pb.x - pb.z * 0.5f, y1 = pb.y - pb.w * 0.5f;
    float x2 = pb.x + pb.z * 0.5f, y2 = pb.y + pb.w * 0.5f;
    float xg1 = tb.x - tb.z * 0.5f, yg1 = tb.y - tb.w * 0.5f;
    float xg2 = tb.x + tb.z * 0.5f, yg2 = tb.y + tb.w * 0.5f;
    float xi1 = fmaxf(x1, xg1), yi1 = fmaxf(y1, yg1);
    float xi2 = fminf(x2, xg2), yi2 = fminf(y2, yg2);
    float inter = fmaxf(xi2 - xi1, 0.f) * fmaxf(yi2 - yi1, 0.f);
    float uni = (x2 - x1) * (y2 - y1) + (xg2 - xg1) * (yg2 - yg1) - inter;
    iou = inter / uni;                    // ops.box_iou: no eps
    float iou_e = inter / (uni + EPSF);   // loss: eps
    float xc1 = fminf(x1, xg1), yc1 = fminf(y1, yg1);
    float xc2 = fmaxf(x2, xg2), yc2 = fmaxf(y2, yg2);
    float dx = xc2 - xc1, dy = yc2 - yc1;
    float diag = dx * dx + dy * dy + EPSF;
    float ex = (x1 + x2 - xg1 - xg2) * 0.5f;
    float ey = (y1 + y2 - yg1 - yg2) * 0.5f;
    float dist = ex * ex + ey * ey;
    diou = 1.f - iou_e + dist / diag;
}

// ---------- K0: per-(b,n) BCE log terms ----------
__global__ __launch_bounds__(256) void k_prep(const float* __restrict__ lp,
                                              float* __restrict__ A,
                                              float* __restrict__ C) {
    int idx = blockIdx.x * 256 + threadIdx.x;  // B*N
    float x = lp[idx];
    float p = 1.f / (1.f + expf(-x));
    A[idx] = -fmaxf(logf(p), -100.f);          // cost when t==1
    C[idx] = -fmaxf(logf(1.f - p), -100.f);    // cost when t==0
}

// ---------- K1: batch-constant label_cost and l1_cost [N,M] ----------
__global__ __launch_bounds__(256) void k_nm(const float* __restrict__ A,
                                            const float* __restrict__ C,
                                            const float* __restrict__ bp,
                                            const float* __restrict__ bt,
                                            const float* __restrict__ lt,
                                            float* __restrict__ lc,
                                            float* __restrict__ l1c) {
    int n = blockIdx.x, m = threadIdx.x;
    float sl = 0.f, s1 = 0.f;
    for (int b = 0; b < BB; ++b) {
        float a = A[b * NN + n];
        float c = C[b * NN + n];
        float t = lt[b * MM + m];
        sl += t * a + (1.f - t) * c;
        float4 P = *reinterpret_cast<const float4*>(bp + ((size_t)b * NN + n) * 4);
        float4 T = *reinterpret_cast<const float4*>(bt + ((size_t)b * MM + m) * 4);
        s1 += fabsf(P.x - T.x) + fabsf(P.y - T.y) + fabsf(P.z - T.z) + fabsf(P.w - T.w);
    }
    lc[n * MM + m]  = sl * (1.f / 64.f);
    l1c[n * MM + m] = s1 * (1.f / 256.f);   // mean over B and 4 coords
}

// ---------- K2: full cost tensor [B,N,M] ----------
__global__ __launch_bounds__(256) void k_cost(const float* __restrict__ bp,
                                              const float* __restrict__ bt,
                                              const float* __restrict__ lc,
                                              const float* __restrict__ l1c,
                                              float* __restrict__ cost) {
    int bn = blockIdx.x;            // b*N + n
    int b = bn >> 8, n = bn & 255;
    int m = threadIdx.x;
    float4 P = *reinterpret_cast<const float4*>(bp + ((size_t)bn) * 4);
    float4 T = *reinterpret_cast<const float4*>(bt + ((size_t)b * MM + m) * 4);
    float iou, diou;
    iou_diou(P, T, iou, diou);
    cost[((size_t)bn << 8) + m] = diou + lc[(n << 8) + m] + l1c[(n << 8) + m];
}

// ---------- K3: Hungarian (Kuhn-Munkres with potentials), one wave per batch ----------
__global__ __launch_bounds__(64) void k_hungarian(const float* __restrict__ cost,
                                                  int* __restrict__ cols) {
    const int b = blockIdx.x;
    const int lane = threadIdx.x;           // 0..63, owns columns 4*lane..4*lane+3
    const float* Cm = cost + (size_t)b * NN * MM;
    __shared__ double u[NN + 1];
    __shared__ int p[NN + 1];
    __shared__ int way[NN + 1];
    const double INFD = __builtin_inf();

    double vj[4] = {0.0, 0.0, 0.0, 0.0};    // v[4*lane+q+1], persists across rows
    double minv[4];

    for (int j = lane; j <= NN; j += 64) { u[j] = 0.0; p[j] = 0; way[j] = 0; }
    __syncthreads();

    for (int i = 1; i <= NN; ++i) {
        if (lane == 0) p[0] = i;
        minv[0] = INFD; minv[1] = INFD; minv[2] = INFD; minv[3] = INFD;
        int used4 = 0;
        int j0 = 0;
        __syncthreads();

        // Dijkstra loop: each iteration marks one column used; <= NN+1 iterations
        for (int it = 0; it <= NN; ++it) {
            if (j0 > 0) {
                int c = j0 - 1;
                if ((c >> 2) == lane) used4 |= 1 << (c & 3);
            }
            int i0 = p[j0];                 // uniform LDS broadcast
            double ui0 = u[i0];
            float4 cr = *reinterpret_cast<const float4*>(Cm + (size_t)(i0 - 1) * MM + 4 * lane);
            float cf0 = cr.x, cf1 = cr.y, cf2 = cr.z, cf3 = cr.w;

            double cand = INFD; int jl = NN + 1;
            #pragma unroll
            for (int q = 0; q < 4; ++q) {
                float cfq = (q == 0) ? cf0 : (q == 1) ? cf1 : (q == 2) ? cf2 : cf3;
                if (!(used4 & (1 << q))) {
                    double cur = ((double)cfq - ui0) - vj[q];
                    if (cur < minv[q]) { minv[q] = cur; way[4 * lane + q + 1] = j0; }
                    if (minv[q] < cand) { cand = minv[q]; jl = 4 * lane + q + 1; }
                }
            }
            // butterfly argmin with smallest-index tie-break (matches np.argmin)
            #pragma unroll
            for (int mm = 1; mm < 64; mm <<= 1) {
                double ov = __shfl_xor(cand, mm);
                int    oj = __shfl_xor(jl, mm);
                if (ov < cand || (ov == cand && oj < jl)) { cand = ov; jl = oj; }
            }
            double delta = cand;
            int j1 = jl;

            // potential updates (u: LDS scatter, distinct rows; v/minv in regs)
            if (lane == 0) u[i] += delta;   // column 0 is "used": p[0] = i
            #pragma unroll
            for (int q = 0; q < 4; ++q) {
                int j = 4 * lane + q + 1;
                if (used4 & (1 << q)) {
                    int pj = p[j];
                    u[pj] += delta;
                    vj[q] -= delta;
                } else {
                    minv[q] -= delta;
                }
            }
            j0 = j1;
            if (p[j0] == 0) break;          // found a free column
        }

        __syncthreads();
        if (lane == 0) {                    // augment along parent pointers
            int jj = j0;
            while (jj) { int jn = way[jj]; p[jj] = p[jn]; jj = jn; }
        }
        __syncthreads();
    }

    // col_of_row[p[j]-1] = j-1
    for (int j = lane + 1; j <= NN; j += 64) cols[b * NN + (p[j] - 1)] = j - 1;
}

// ---------- K4: matched losses, per-block (batch) partial sums ----------
__global__ __launch_bounds__(256) void k_loss(const float* __restrict__ lp,
                                              const float* __restrict__ bp,
                                              const float* __restrict__ lt,
                                              const float* __restrict__ bt,
                                              const int* __restrict__ cols,
                                              float* __restrict__ partials) {
    int b = blockIdx.x, n = threadIdx.x;
    int col = cols[b * NN + n];
    float x = lp[b * NN + n];
    float pp = 1.f / (1.f + expf(-x));
    float t = lt[b * MM + col];
    float4 P = *reinterpret_cast<const float4*>(bp + ((size_t)b * NN + n) * 4);
    float4 T = *reinterpret_cast<const float4*>(bt + ((size_t)b * MM + col) * 4);
    float w = (t == 1.f) ? 1.f : 0.f;
    float iou, diou;
    iou_diou(P, T, iou, diou);
    float bce = -(t * fmaxf(logf(pp), -100.f) + (1.f - t) * fmaxf(logf(1.f - pp), -100.f));
    float l1 = fabsf(P.x - T.x) + fabsf(P.y - T.y) + fabsf(P.z - T.z) + fabsf(P.w - T.w);

    float v0 = w, v1 = diou * w, v2 = iou * w, v3 = bce, v4 = l1 * w;
    #pragma unroll
    for (int mm = 1; mm < 64; mm <<= 1) {
        v0 += __shfl_xor(v0, mm); v1 += __shfl_xor(v1, mm);
        v2 += __shfl_xor(v2, mm); v3 += __shfl_xor(v3, mm);
        v4 += __shfl_xor(v4, mm);
    }
    __shared__ float red[4][5];
    int wid = n >> 6, lane = n & 63;
    if (lane == 0) { red[wid][0] = v0; red[wid][1] = v1; red[wid][2] = v2; red[wid][3] = v3; red[wid][4] = v4; }
    __syncthreads();
    if (n == 0) {
        float s0 = red[0][0] + red[1][0] + red[2][0] + red[3][0];
        float s1 = red[0][1] + red[1][1] + red[2][1] + red[3][1];
        float s2 = red[0][2] + red[1][2] + red[2][2] + red[3][2];
        float s3 = red[0][3] + red[1][3] + red[2][3] + red[3][3];
        float s4 = red[0][4] + red[1][4] + red[2][4] + red[3][4];
        partials[b * 8 + 0] = s0; partials[b * 8 + 1] = s1; partials[b * 8 + 2] = s2;
        partials[b * 8 + 3] = s3; partials[b * 8 + 4] = s4;
    }
}

// ---------- K5: final scalar combine ----------
__global__ __launch_bounds__(64) void k_final(const float* __restrict__ partials,
                                              float* __restrict__ out) {
    int t = threadIdx.x;  // 64 blocks' partials
    float v0 = partials[t * 8 + 0], v1 = partials[t * 8 + 1], v2 = partials[t * 8 + 2];
    float v3 = partials[t * 8 + 3], v4 = partials[t * 8 + 4];
    #pragma unroll
    for (int mm = 1; mm < 64; mm <<= 1) {
        v0 += __shfl_xor(v0, mm); v1 += __shfl_xor(v1, mm);
        v2 += __shfl_xor(v2, mm); v3 += __shfl_xor(v3, mm);
        v4 += __shfl_xor(v4, mm);
    }
    if (t == 0) {
        float wsum = v0;
        float diou_loss = v1 / wsum;
        float iou = v2 / wsum;
        float label_loss = v3 * (1.f / (64.f * 256.f));
        float bbox_loss = v4 / (wsum * 4.f);
        out[0] = diou_loss + label_loss + bbox_loss;
        out[1] = iou;
    }
}

extern "C" void kernel_launch(void* const* d_in, const int* in_sizes, int n_in,
                              void* d_out, int out_size, void* d_ws, size_t ws_size,
                              hipStream_t stream) {
    const float* labels_pred   = (const float*)d_in[0];  // [B,N,1]
    const float* bbox_pred     = (const float*)d_in[1];  // [B,N,4]
    const float* labels_target = (const float*)d_in[2];  // [B,M]
    const float* bbox_target   = (const float*)d_in[3];  // [B,M,4]
    float* out = (float*)d_out;

    float* A    = (float*)d_ws;            // [B*N]
    float* C    = A + BB * NN;             // [B*N]
    float* lc   = C + BB * NN;             // [N*M]
    float* l1c  = lc + NN * MM;            // [N*M]
    float* cost = l1c + NN * MM;           // [B*N*M]
    int*   cols = (int*)(cost + (size_t)BB * NN * MM);   // [B*N]
    float* partials = (float*)(cols + BB * NN);          // [B*8]

    k_prep<<<BB * NN / 256, 256, 0, stream>>>(labels_pred, A, C);
    k_nm<<<NN, MM, 0, stream>>>(A, C, bbox_pred, bbox_target, labels_target, lc, l1c);
    k_cost<<<BB * NN, MM, 0, stream>>>(bbox_pred, bbox_target, lc, l1c, cost);
    k_hungarian<<<BB, 64, 0, stream>>>(cost, cols);
    k_loss<<<BB, NN, 0, stream>>>(labels_pred, bbox_pred, labels_target, bbox_target, cols, partials);
    k_final<<<1, 64, 0, stream>>>(partials, out);
}

// Round 2
// 3903.561 us; speedup vs baseline: 1.8325x; 1.8325x over previous
//
#include <hip/hip_runtime.h>
#include <math.h>

#define BB 64
#define NN 256
#define MM 256
#define EPSF 1e-7f

// ---------- helpers ----------

__device__ __forceinline__ void iou_diou(const float4 pb, const float4 tb,
                                         float& iou, float& diou) {
    float x1 = pb.x - pb.z * 0.5f, y1 = pb.y - pb.w * 0.5f;
    float x2 = pb.x + pb.z * 0.5f, y2 = pb.y + pb.w * 0.5f;
    float xg1 = tb.x - tb.z * 0.5f, yg1 = tb.y - tb.w * 0.5f;
    float xg2 = tb.x + tb.z * 0.5f, yg2 = tb.y + tb.w * 0.5f;
    float xi1 = fmaxf(x1, xg1), yi1 = fmaxf(y1, yg1);
    float xi2 = fminf(x2, xg2), yi2 = fminf(y2, yg2);
    float inter = fmaxf(xi2 - xi1, 0.f) * fmaxf(yi2 - yi1, 0.f);
    float uni = (x2 - x1) * (y2 - y1) + (xg2 - xg1) * (yg2 - yg1) - inter;
    iou = inter / uni;
    float iou_e = inter / (uni + EPSF);
    float xc1 = fminf(x1, xg1), yc1 = fminf(y1, yg1);
    float xc2 = fmaxf(x2, xg2), yc2 = fmaxf(y2, yg2);
    float dx = xc2 - xc1, dy = yc2 - yc1;
    float diag = dx * dx + dy * dy + EPSF;
    float ex = (x1 + x2 - xg1 - xg2) * 0.5f;
    float ey = (y1 + y2 - yg1 - yg2) * 0.5f;
    float dist = ex * ex + ey * ey;
    diou = 1.f - iou_e + dist / diag;
}

// monotone double -> u64 key, low 9 bits replaced by column index (1..256).
__device__ __forceinline__ unsigned long long dkey(double d, int j) {
    unsigned long long b = (unsigned long long)__double_as_longlong(d);
    b ^= (b >> 63) ? 0xFFFFFFFFFFFFFFFFULL : 0x8000000000000000ULL;
    return (b & ~511ULL) | (unsigned long long)j;
}
__device__ __forceinline__ double unkey(unsigned long long k) {
    unsigned long long b = k & ~511ULL;
    b ^= (b & 0x8000000000000000ULL) ? 0x8000000000000000ULL : 0xFFFFFFFFFFFFFFFFULL;
    return __longlong_as_double((long long)b);
}

#define SEL4I(s, a0, a1, a2, a3) ((s) == 0 ? (a0) : (s) == 1 ? (a1) : (s) == 2 ? (a2) : (a3))
#define SEL4D(s, a0, a1, a2, a3) ((s) == 0 ? (a0) : (s) == 1 ? (a1) : (s) == 2 ? (a2) : (a3))

// ---------- K0: per-(b,n) BCE log terms ----------
__global__ __launch_bounds__(256) void k_prep(const float* __restrict__ lp,
                                              float* __restrict__ A,
                                              float* __restrict__ C) {
    int idx = blockIdx.x * 256 + threadIdx.x;
    float x = lp[idx];
    float p = 1.f / (1.f + expf(-x));
    A[idx] = -fmaxf(logf(p), -100.f);
    C[idx] = -fmaxf(logf(1.f - p), -100.f);
}

// ---------- K1: batch-constant label_cost and l1_cost [N,M] ----------
__global__ __launch_bounds__(256) void k_nm(const float* __restrict__ A,
                                            const float* __restrict__ C,
                                            const float* __restrict__ bp,
                                            const float* __restrict__ bt,
                                            const float* __restrict__ lt,
                                            float* __restrict__ lc,
                                            float* __restrict__ l1c) {
    int n = blockIdx.x, m = threadIdx.x;
    float sl = 0.f, s1 = 0.f;
    for (int b = 0; b < BB; ++b) {
        float a = A[b * NN + n];
        float c = C[b * NN + n];
        float t = lt[b * MM + m];
        sl += t * a + (1.f - t) * c;
        float4 P = *reinterpret_cast<const float4*>(bp + ((size_t)b * NN + n) * 4);
        float4 T = *reinterpret_cast<const float4*>(bt + ((size_t)b * MM + m) * 4);
        s1 += fabsf(P.x - T.x) + fabsf(P.y - T.y) + fabsf(P.z - T.z) + fabsf(P.w - T.w);
    }
    lc[n * MM + m]  = sl * (1.f / 64.f);
    l1c[n * MM + m] = s1 * (1.f / 256.f);
}

// ---------- K2: full cost tensor [B,N,M] ----------
__global__ __launch_bounds__(256) void k_cost(const float* __restrict__ bp,
                                              const float* __restrict__ bt,
                                              const float* __restrict__ lc,
                                              const float* __restrict__ l1c,
                                              float* __restrict__ cost) {
    int bn = blockIdx.x;
    int b = bn >> 8, n = bn & 255;
    int m = threadIdx.x;
    float4 P = *reinterpret_cast<const float4*>(bp + ((size_t)bn) * 4);
    float4 T = *reinterpret_cast<const float4*>(bt + ((size_t)b * MM + m) * 4);
    float iou, diou;
    iou_diou(P, T, iou, diou);
    cost[((size_t)bn << 8) + m] = diou + lc[(n << 8) + m] + l1c[(n << 8) + m];
}

// ---------- K3: exact LAP (successive shortest paths, LAPJV-style init) ----------
// One wave per batch. Lane owns columns 4*lane+q+1 (1-based), q=0..3.
// All per-column state (v, u[p], p, way, minv) in registers; argmin via
// 64-lane butterfly on a packed monotone u64 key carrying (p, up) payload.
__global__ __launch_bounds__(64) void k_hungarian(const float* __restrict__ cost,
                                                  int* __restrict__ cols) {
    const int b = blockIdx.x;
    const int lane = threadIdx.x;
    const float* Cm = cost + (size_t)b * NN * MM;
    const unsigned long long MAXK = 0xFFFFFFFFFFFFFFFFULL;
    const double INFD = __builtin_inf();

    __shared__ int jofrow[NN + 1];   // smallest column (1-based) whose argmin is this row
    for (int r = lane; r <= NN; r += 64) jofrow[r] = 0x7fffffff;
    __syncthreads();

    // ---- column reduction: v[j] = min_i c[i][j], remember argmin row ----
    float cm0 = __builtin_inff(), cm1 = cm0, cm2 = cm0, cm3 = cm0;
    int rm0 = 0, rm1 = 0, rm2 = 0, rm3 = 0;
    #pragma unroll 4
    for (int i = 0; i < NN; ++i) {
        float4 cr = *reinterpret_cast<const float4*>(Cm + (size_t)i * MM + 4 * lane);
        if (cr.x < cm0) { cm0 = cr.x; rm0 = i; }
        if (cr.y < cm1) { cm1 = cr.y; rm1 = i; }
        if (cr.z < cm2) { cm2 = cr.z; rm2 = i; }
        if (cr.w < cm3) { cm3 = cr.w; rm3 = i; }
    }
    atomicMin(&jofrow[rm0 + 1], 4 * lane + 1);
    atomicMin(&jofrow[rm1 + 1], 4 * lane + 2);
    atomicMin(&jofrow[rm2 + 1], 4 * lane + 3);
    atomicMin(&jofrow[rm3 + 1], 4 * lane + 4);
    __syncthreads();

    // ---- greedy pre-assignment + register state init ----
    double vj0 = cm0, vj1 = cm1, vj2 = cm2, vj3 = cm3;   // v[j]
    double up0 = 0.0, up1 = 0.0, up2 = 0.0, up3 = 0.0;   // u[p[j]]
    int pj0_ = (jofrow[rm0 + 1] == 4 * lane + 1) ? rm0 + 1 : 0;
    int pj1_ = (jofrow[rm1 + 1] == 4 * lane + 2) ? rm1 + 1 : 0;
    int pj2_ = (jofrow[rm2 + 1] == 4 * lane + 3) ? rm2 + 1 : 0;
    int pj3_ = (jofrow[rm3 + 1] == 4 * lane + 4) ? rm3 + 1 : 0;
    int wy0 = 0, wy1 = 0, wy2 = 0, wy3 = 0;              // way[j]

    // assigned-row bitmasks (wave-uniform)
    unsigned long long am0 = __ballot(jofrow[1 + lane]       != 0x7fffffff);
    unsigned long long am1 = __ballot(jofrow[1 + 64 + lane]  != 0x7fffffff);
    unsigned long long am2 = __ballot(jofrow[1 + 128 + lane] != 0x7fffffff);
    unsigned long long am3 = __ballot(jofrow[1 + 192 + lane] != 0x7fffffff);

    for (int i = 1; i <= NN; ++i) {
        unsigned long long am = (i <= 64) ? am0 : (i <= 128) ? am1 : (i <= 192) ? am2 : am3;
        if ((am >> ((i - 1) & 63)) & 1ULL) continue;   // row pre-assigned

        double u_i = 0.0;
        double mv0 = INFD, mv1 = INFD, mv2 = INFD, mv3 = INFD;
        int used4 = 0;
        int j0 = 0;
        int i0 = i;
        double ui0 = 0.0;

        for (int it = 0; it <= NN; ++it) {
            float4 cr = *reinterpret_cast<const float4*>(Cm + (size_t)(i0 - 1) * MM + 4 * lane);
            if (!(used4 & 1)) { double cur = ((double)cr.x - ui0) - vj0; if (cur < mv0) { mv0 = cur; wy0 = j0; } }
            if (!(used4 & 2)) { double cur = ((double)cr.y - ui0) - vj1; if (cur < mv1) { mv1 = cur; wy1 = j0; } }
            if (!(used4 & 4)) { double cur = ((double)cr.z - ui0) - vj2; if (cur < mv2) { mv2 = cur; wy2 = j0; } }
            if (!(used4 & 8)) { double cur = ((double)cr.w - ui0) - vj3; if (cur < mv3) { mv3 = cur; wy3 = j0; } }

            unsigned long long k0 = (used4 & 1) ? MAXK : dkey(mv0, 4 * lane + 1);
            unsigned long long k1 = (used4 & 2) ? MAXK : dkey(mv1, 4 * lane + 2);
            unsigned long long k2 = (used4 & 4) ? MAXK : dkey(mv2, 4 * lane + 3);
            unsigned long long k3 = (used4 & 8) ? MAXK : dkey(mv3, 4 * lane + 4);

            // local payload reduce (value-then-smallest-j via key low bits)
            unsigned long long ka; int pa; double ua;
            if (k1 < k0) { ka = k1; pa = pj1_; ua = up1; } else { ka = k0; pa = pj0_; ua = up0; }
            unsigned long long kb; int pb; double ub;
            if (k3 < k2) { kb = k3; pb = pj3_; ub = up3; } else { kb = k2; pb = pj2_; ub = up2; }
            if (kb < ka) { ka = kb; pa = pb; ua = ub; }

            // 64-lane butterfly min, carrying (p, up) payload
            #pragma unroll
            for (int mmm = 1; mmm < 64; mmm <<= 1) {
                unsigned long long ok = __shfl_xor(ka, mmm);
                int op = __shfl_xor(pa, mmm);
                double ou = __shfl_xor(ua, mmm);
                if (ok < ka) { ka = ok; pa = op; ua = ou; }
            }
            double delta = unkey(ka);
            int j1 = (int)(ka & 511ULL);

            u_i += delta;
            if (used4 & 1) { up0 += delta; vj0 -= delta; } else { mv0 -= delta; }
            if (used4 & 2) { up1 += delta; vj1 -= delta; } else { mv1 -= delta; }
            if (used4 & 4) { up2 += delta; vj2 -= delta; } else { mv2 -= delta; }
            if (used4 & 8) { up3 += delta; vj3 -= delta; } else { mv3 -= delta; }

            j0 = j1;
            if (pa == 0) break;            // reached a free column
            int ci = j1 - 1;
            if ((ci >> 2) == lane) used4 |= 1 << (ci & 3);
            i0 = pa;
            ui0 = ua;
        }

        // ---- augment along way pointers (jj uniform; cross-lane via shfl) ----
        int jj = j0;
        while (jj) {
            int o = (jj - 1) >> 2, s = (jj - 1) & 3;
            int wv = SEL4I(s, wy0, wy1, wy2, wy3);
            int jn = __shfl(wv, o);
            int pn; double un;
            if (jn == 0) { pn = i; un = u_i; }
            else {
                int o2 = (jn - 1) >> 2, s2 = (jn - 1) & 3;
                int pv = SEL4I(s2, pj0_, pj1_, pj2_, pj3_);
                double uv = SEL4D(s2, up0, up1, up2, up3);
                pn = __shfl(pv, o2);
                un = __shfl(uv, o2);
            }
            if (lane == o) {
                if (s == 0)      { pj0_ = pn; up0 = un; }
                else if (s == 1) { pj1_ = pn; up1 = un; }
                else if (s == 2) { pj2_ = pn; up2 = un; }
                else             { pj3_ = pn; up3 = un; }
            }
            jj = jn;
        }
    }

    // col_of_row: cols[p[j]-1] = j-1
    cols[b * NN + (pj0_ - 1)] = 4 * lane + 0;
    cols[b * NN + (pj1_ - 1)] = 4 * lane + 1;
    cols[b * NN + (pj2_ - 1)] = 4 * lane + 2;
    cols[b * NN + (pj3_ - 1)] = 4 * lane + 3;
}

// ---------- K4: matched losses, per-block (batch) partial sums ----------
__global__ __launch_bounds__(256) void k_loss(const float* __restrict__ lp,
                                              const float* __restrict__ bp,
                                              const float* __restrict__ lt,
                                              const float* __restrict__ bt,
                                              const int* __restrict__ cols,
                                              float* __restrict__ partials) {
    int b = blockIdx.x, n = threadIdx.x;
    int col = cols[b * NN + n];
    float x = lp[b * NN + n];
    float pp = 1.f / (1.f + expf(-x));
    float t = lt[b * MM + col];
    float4 P = *reinterpret_cast<const float4*>(bp + ((size_t)b * NN + n) * 4);
    float4 T = *reinterpret_cast<const float4*>(bt + ((size_t)b * MM + col) * 4);
    float w = (t == 1.f) ? 1.f : 0.f;
    float iou, diou;
    iou_diou(P, T, iou, diou);
    float bce = -(t * fmaxf(logf(pp), -100.f) + (1.f - t) * fmaxf(logf(1.f - pp), -100.f));
    float l1 = fabsf(P.x - T.x) + fabsf(P.y - T.y) + fabsf(P.z - T.z) + fabsf(P.w - T.w);

    float v0 = w, v1 = diou * w, v2 = iou * w, v3 = bce, v4 = l1 * w;
    #pragma unroll
    for (int mm = 1; mm < 64; mm <<= 1) {
        v0 += __shfl_xor(v0, mm); v1 += __shfl_xor(v1, mm);
        v2 += __shfl_xor(v2, mm); v3 += __shfl_xor(v3, mm);
        v4 += __shfl_xor(v4, mm);
    }
    __shared__ float red[4][5];
    int wid = n >> 6, lane = n & 63;
    if (lane == 0) { red[wid][0] = v0; red[wid][1] = v1; red[wid][2] = v2; red[wid][3] = v3; red[wid][4] = v4; }
    __syncthreads();
    if (n == 0) {
        float s0 = red[0][0] + red[1][0] + red[2][0] + red[3][0];
        float s1 = red[0][1] + red[1][1] + red[2][1] + red[3][1];
        float s2 = red[0][2] + red[1][2] + red[2][2] + red[3][2];
        float s3 = red[0][3] + red[1][3] + red[2][3] + red[3][3];
        float s4 = red[0][4] + red[1][4] + red[2][4] + red[3][4];
        partials[b * 8 + 0] = s0; partials[b * 8 + 1] = s1; partials[b * 8 + 2] = s2;
        partials[b * 8 + 3] = s3; partials[b * 8 + 4] = s4;
    }
}

// ---------- K5: final scalar combine ----------
__global__ __launch_bounds__(64) void k_final(const float* __restrict__ partials,
                                              float* __restrict__ out) {
    int t = threadIdx.x;
    float v0 = partials[t * 8 + 0], v1 = partials[t * 8 + 1], v2 = partials[t * 8 + 2];
    float v3 = partials[t * 8 + 3], v4 = partials[t * 8 + 4];
    #pragma unroll
    for (int mm = 1; mm < 64; mm <<= 1) {
        v0 += __shfl_xor(v0, mm); v1 += __shfl_xor(v1, mm);
        v2 += __shfl_xor(v2, mm); v3 += __shfl_xor(v3, mm);
        v4 += __shfl_xor(v4, mm);
    }
    if (t == 0) {
        float wsum = v0;
        float diou_loss = v1 / wsum;
        float iou = v2 / wsum;
        float label_loss = v3 * (1.f / (64.f * 256.f));
        float bbox_loss = v4 / (wsum * 4.f);
        out[0] = diou_loss + label_loss + bbox_loss;
        out[1] = iou;
    }
}

extern "C" void kernel_launch(void* const* d_in, const int* in_sizes, int n_in,
                              void* d_out, int out_size, void* d_ws, size_t ws_size,
                              hipStream_t stream) {
    const float* labels_pred   = (const float*)d_in[0];
    const float* bbox_pred     = (const float*)d_in[1];
    const float* labels_target = (const float*)d_in[2];
    const float* bbox_target   = (const float*)d_in[3];
    float* out = (float*)d_out;

    float* A    = (float*)d_ws;
    float* C    = A + BB * NN;
    float* lc   = C + BB * NN;
    float* l1c  = lc + NN * MM;
    float* cost = l1c + NN * MM;
    int*   cols = (int*)(cost + (size_t)BB * NN * MM);
    float* partials = (float*)(cols + BB * NN);

    k_prep<<<BB * NN / 256, 256, 0, stream>>>(labels_pred, A, C);
    k_nm<<<NN, MM, 0, stream>>>(A, C, bbox_pred, bbox_target, labels_target, lc, l1c);
    k_cost<<<BB * NN, MM, 0, stream>>>(bbox_pred, bbox_target, lc, l1c, cost);
    k_hungarian<<<BB, 64, 0, stream>>>(cost, cols);
    k_loss<<<BB, NN, 0, stream>>>(labels_pred, bbox_pred, labels_target, bbox_target, cols, partials);
    k_final<<<1, 64, 0, stream>>>(partials, out);
}